// Round 4
// baseline (10479.234 us; speedup 1.0000x reference)
//
#include <hip/hip_runtime.h>
#include <cstddef>
#include <cstdint>

// Problem constants
#define PP 32       // particles
#define BB 64       // batch
#define TT 100      // time steps
#define WW 50       // window
#define EE 64       // embed
#define HH 256      // hidden
// ALPHA = 0.5, (1-ALPHA)/P = 0.015625

#define KPAD 360    // padded K rows in packed weights (320 real + 40 pad)

typedef float f4 __attribute__((ext_vector_type(4)));

__device__ __forceinline__ float sigm(float x) { return 1.0f / (1.0f + expf(-x)); }
__device__ __forceinline__ float softplusf(float x) {
    return fmaxf(x, 0.0f) + log1pf(expf(-fabsf(x)));
}

// ---------------------------------------------------------------------------
// Prologue A: emb[t,b,:] = relu(prev_window[b,t,:] @ W_act + b_act)
// also xobs[t*64+b] = emb . W_obs[256:320] + b_obs
// ---------------------------------------------------------------------------
__global__ __launch_bounds__(256) void k_emb(
    const float* __restrict__ pw, const float* __restrict__ w_act,
    const float* __restrict__ b_act, const float* __restrict__ w_obs,
    const float* __restrict__ b_obs, float* __restrict__ embT,
    float* __restrict__ xobs)
{
    int tid = threadIdx.x;
    int sub = tid >> 6;          // 0..3 (one wave per (b,t))
    int e   = tid & 63;
    int bt  = blockIdx.x * 4 + sub;   // = b*100 + t
    int b = bt / TT, t = bt % TT;

    __shared__ float pws[4][WW + 2];
    if (e < WW) pws[sub][e] = pw[(size_t)bt * WW + e];
    __syncthreads();

    float acc = b_act[e];
    #pragma unroll 5
    for (int w = 0; w < WW; ++w) acc += pws[sub][w] * w_act[w * EE + e];
    float r = fmaxf(acc, 0.0f);
    embT[((size_t)t * BB + b) * EE + e] = r;

    float xv = r * w_obs[HH + e];
    #pragma unroll
    for (int d = 1; d < 64; d <<= 1) xv += __shfl_xor(xv, d);
    if (e == 0) xobs[t * BB + b] = xv + b_obs[0];
}

// ---------------------------------------------------------------------------
// Prologue B: pack weights per col-tile, contiguous 80 floats (320 B) per k.
// Wp2[(ct*KPAD + k)*80 + j], j = wu*20 + lh*5 + g,
//   col = g*256 + ct*16 + wu*4 + lh ; k<256 from W_hh, 256..319 from W_ih,
//   k>=320 zero pad (prefetch overshoot target, never consumed).
// ---------------------------------------------------------------------------
__global__ __launch_bounds__(256) void k_pack(
    const float* __restrict__ W_ih, const float* __restrict__ W_hh,
    float* __restrict__ Wp2)
{
    int i = blockIdx.x * 256 + threadIdx.x;     // 16*KPAD*80 = 460800 total
    int ct  = i / (KPAD * 80);
    int rem = i - ct * (KPAD * 80);
    int k   = rem / 80;
    int j   = rem - k * 80;
    int wu  = j / 20;
    int jj  = j - wu * 20;
    int lh  = jj / 5, g = jj - lh * 5;
    int col = g * HH + ct * 16 + wu * 4 + lh;
    float v = 0.0f;
    if (k < HH)            v = W_hh[(size_t)k * 1280 + col];
    else if (k < HH + EE)  v = W_ih[(size_t)(k - HH) * 1280 + col];
    Wp2[i] = v;
}

// ---------------------------------------------------------------------------
// S1: recurrent GEMM + LSTM elementwise + partial output dots.
// grid (32 particles, 16 col-tiles) x 256 threads (4 waves), 2 blocks/CU.
// lane = row (batch b); wave wu owns 4 hcols x 5 gates = 20 packed cols.
// A: LDS-staged 32-k chunk -> 32 VGPRs (no DS ops in inner loop).
// B: per-lane global_load_dwordx4 (divergence-forced voffset kills SMEM),
//    depth-4 rotating prefetch, compiler-counted vmcnt.
// ---------------------------------------------------------------------------
#define LOADK(Bq, KN) do { \
    const float* p_ = sb + voff + (KN) * 80; \
    Bq[0] = *(const f4*)(p_ +  0); \
    Bq[1] = *(const f4*)(p_ +  4); \
    Bq[2] = *(const f4*)(p_ +  8); \
    Bq[3] = *(const f4*)(p_ + 12); \
    Bq[4] = *(const f4*)(p_ + 16); \
} while (0)

#define FMA20(av, Bq) do { float a_v = (av); \
    acc[ 0]+=a_v*Bq[0].x; acc[ 1]+=a_v*Bq[0].y; acc[ 2]+=a_v*Bq[0].z; acc[ 3]+=a_v*Bq[0].w; \
    acc[ 4]+=a_v*Bq[1].x; acc[ 5]+=a_v*Bq[1].y; acc[ 6]+=a_v*Bq[1].z; acc[ 7]+=a_v*Bq[1].w; \
    acc[ 8]+=a_v*Bq[2].x; acc[ 9]+=a_v*Bq[2].y; acc[10]+=a_v*Bq[2].z; acc[11]+=a_v*Bq[2].w; \
    acc[12]+=a_v*Bq[3].x; acc[13]+=a_v*Bq[3].y; acc[14]+=a_v*Bq[3].z; acc[15]+=a_v*Bq[3].w; \
    acc[16]+=a_v*Bq[4].x; acc[17]+=a_v*Bq[4].y; acc[18]+=a_v*Bq[4].z; acc[19]+=a_v*Bq[4].w; \
} while (0)

__global__ __launch_bounds__(256, 2) void s1_kernel(
    const float* __restrict__ h_in, const float* __restrict__ c_in,
    const int* __restrict__ gidx,            // null at t=0 (identity)
    const float* __restrict__ embT_t,
    const float* __restrict__ Wp2,
    const float* __restrict__ b_ih, const float* __restrict__ b_hh,
    const float* __restrict__ w_obs, const float* __restrict__ w_lab,
    const float* __restrict__ eps_t,
    float* __restrict__ h1o, float* __restrict__ c1o,
    float* __restrict__ dpo, float* __restrict__ dpl)   // [16][2048] each
{
    __shared__ float lA[32][66];      // [k][row]; read lA[k][lane] conflict-free
    __shared__ int   lidx[64];
    __shared__ float ldot[4][64][2];

    int tid  = threadIdx.x;
    int row0 = blockIdx.x * 64;       // particle p = blockIdx.x
    int ct   = blockIdx.y;            // col-tile 0..15 (16 hcols each)
    int lane = tid & 63;
    int wu   = __builtin_amdgcn_readfirstlane(tid >> 6);   // wave id 0..3

    if (tid < 64) lidx[tid] = gidx ? gidx[row0 + tid] : (row0 + tid);

    float acc[20];
    #pragma unroll
    for (int c = 0; c < 20; ++c) acc[c] = 0.0f;

    // uniform (per-wave) base of this wave's packed B columns
    const float* sb = Wp2 + (size_t)ct * (KPAD * 80) + wu * 20;

    int r  = tid >> 2;          // staging row 0..63
    int q4 = (tid & 3) * 4;     // float offset within 16

    __syncthreads();            // lidx ready

    const float* aA = h_in + (size_t)lidx[r] * HH;   // gather-on-read row base
    const float* aE = embT_t + (size_t)r * EE;

    // depth-4 rotating B prefetch for k = 0..3
    f4 B0[5], B1[5], B2[5], B3[5];
    {
        unsigned voff = 0u;
        asm volatile("" : "+v"(voff));   // divergence-force: VMEM, not SMEM
        LOADK(B0, 0); LOADK(B1, 1); LOADK(B2, 2); LOADK(B3, 3);
    }

    for (int kc = 0; kc < 10; ++kc) {
        // ---- stage A chunk (64 rows x 32 k) into LDS, transposed
        #pragma unroll
        for (int it = 0; it < 2; ++it) {
            int kf = q4 + it * 16;
            f4 v;
            if (kc < 8) v = *(const f4*)(aA + kc * 32 + kf);
            else        v = *(const f4*)(aE + (kc - 8) * 32 + kf);
            lA[kf + 0][r] = v.x;
            lA[kf + 1][r] = v.y;
            lA[kf + 2][r] = v.z;
            lA[kf + 3][r] = v.w;
        }
        __syncthreads();

        float a_[32];
        #pragma unroll
        for (int k2 = 0; k2 < 32; ++k2) a_[k2] = lA[k2][lane];

        unsigned voff = (unsigned)(kc * 32 * 80);
        asm volatile("" : "+v"(voff));   // divergence-force per chunk

        #pragma unroll
        for (int kk = 0; kk < 32; kk += 4) {
            FMA20(a_[kk + 0], B0); LOADK(B0, kk + 4);   // prefetch k+4 (crosses
            FMA20(a_[kk + 1], B1); LOADK(B1, kk + 5);   //  into next chunk /
            FMA20(a_[kk + 2], B2); LOADK(B2, kk + 6);   //  zero-pad at end)
            FMA20(a_[kk + 3], B3); LOADK(B3, kk + 7);
        }
        __syncthreads();
    }

    // ---- epilogue: thread (wave wu, lane=row) owns hcols ct*16 + wu*4 .. +4
    int row    = row0 + lane;
    int srcrow = lidx[lane];
    int hc0    = ct * 16 + wu * 4;

    f4 cin  = *(const f4*)&c_in[(size_t)srcrow * HH + hc0];
    f4 epsv = *(const f4*)&eps_t[(size_t)row * HH + hc0];
    float cps[4]  = {cin.x, cin.y, cin.z, cin.w};
    float eps4[4] = {epsv.x, epsv.y, epsv.z, epsv.w};
    float c1s[4], h1s[4];
    float pdo = 0.0f, pdl = 0.0f;

    #pragma unroll
    for (int l = 0; l < 4; ++l) {
        int hcol = hc0 + l;
        float gi = acc[l*5+0] + b_ih[0*HH+hcol] + b_hh[0*HH+hcol];
        float gf = acc[l*5+1] + b_ih[1*HH+hcol] + b_hh[1*HH+hcol];
        float gg = acc[l*5+2] + b_ih[2*HH+hcol] + b_hh[2*HH+hcol];
        float go = acc[l*5+3] + b_ih[3*HH+hcol] + b_hh[3*HH+hcol];
        float gv = acc[l*5+4] + b_ih[4*HH+hcol] + b_hh[4*HH+hcol];

        float mu  = sigm(gf) * cps[l] + sigm(gi) * tanhf(gg);
        float c1v = mu + softplusf(gv) * eps4[l];
        float h1v = sigm(go) * tanhf(c1v);
        c1s[l] = c1v; h1s[l] = h1v;
        pdo += h1v * w_obs[hcol];
        pdl += h1v * w_lab[hcol];
    }
    f4 c1v4 = {c1s[0], c1s[1], c1s[2], c1s[3]};
    f4 h1v4 = {h1s[0], h1s[1], h1s[2], h1s[3]};
    *(f4*)&c1o[(size_t)row * HH + hc0] = c1v4;
    *(f4*)&h1o[(size_t)row * HH + hc0] = h1v4;

    ldot[wu][lane][0] = pdo;
    ldot[wu][lane][1] = pdl;
    __syncthreads();
    if (tid < 64) {
        float so = 0.0f, sl = 0.0f;
        #pragma unroll
        for (int w2 = 0; w2 < 4; ++w2) { so += ldot[w2][tid][0]; sl += ldot[w2][tid][1]; }
        dpo[ct * 2048 + row0 + tid] = so;
        dpl[ct * 2048 + row0 + tid] = sl;
    }
}

// ---------------------------------------------------------------------------
// S2: per batch-column b (64 blocks x 256 thr): reduce 16 partial dots,
// log-softmax over P, gumbel-argmax, write gidx, emit pf_out and y_out.
// ---------------------------------------------------------------------------
__global__ __launch_bounds__(256) void s2_kernel(
    const float* __restrict__ dpo, const float* __restrict__ dpl,
    const float* __restrict__ xobs_t, const float* __restrict__ g_t,
    const float* __restrict__ b_lab,
    float* __restrict__ p_buf, int first,
    int* __restrict__ gidx_next,
    float* __restrict__ y_out_t, float* __restrict__ pf_out_t)
{
    int b   = blockIdx.x;
    int tid = threadIdx.x;

    __shared__ float gt[PP][PP + 1];
    __shared__ float lg[PP];
    __shared__ float w1s[PP];
    __shared__ float lgt[PP];
    __shared__ float pnew[PP];
    __shared__ float dpart[PP];
    __shared__ int   idxs[PP];

    // stage gumbel tile (32x32), 256 threads x 1 float4
    {
        f4 v = ((const f4*)(g_t + (size_t)b * 1024))[tid];
        int p = tid >> 3, j0 = (tid & 7) * 4;
        gt[p][j0 + 0] = v.x; gt[p][j0 + 1] = v.y;
        gt[p][j0 + 2] = v.z; gt[p][j0 + 3] = v.w;
    }

    int p = tid >> 3, j = tid & 7;
    // reduce 16 dpo partials: thread (p, j) takes ct = j and j+8
    {
        int o = p * BB + b;
        float s = dpo[j * 2048 + o] + dpo[(j + 8) * 2048 + o];
        s += __shfl_xor(s, 1); s += __shfl_xor(s, 2); s += __shfl_xor(s, 4);
        if (j == 0) {
            float pprev = first ? -3.4657359027997265f : p_buf[o];
            lg[p] = pprev + s + xobs_t[b];
        }
    }
    __syncthreads();

    // log-softmax over P; w1; logits
    if (tid < 32) {
        float v = lg[tid];
        float m = v;
        #pragma unroll
        for (int d = 1; d < 32; d <<= 1) m = fmaxf(m, __shfl_xor(m, d));
        float e = expf(v - m), se = e;
        #pragma unroll
        for (int d = 1; d < 32; d <<= 1) se += __shfl_xor(se, d);
        float l1 = v - m - logf(se);
        float w1 = expf(l1);
        w1s[tid] = w1;
        lgt[tid] = logf(0.5f * w1 + 0.015625f);
    }
    __syncthreads();

    // gumbel-argmax resample; new weights; p_new
    if (tid < 32) {
        int p2 = tid;
        float best = -INFINITY; int bi = 0;
        #pragma unroll 8
        for (int jj = 0; jj < 32; ++jj) {
            float val = lgt[jj] + gt[p2][jj];
            if (val > best) { best = val; bi = jj; }   // first max, like jnp.argmax
        }
        idxs[p2] = bi;
        gidx_next[p2 * BB + b] = bi * BB + b;

        float wv = w1s[bi];
        wv = wv / (0.5f * wv + 0.015625f);
        float lw = logf(wv);
        float m2 = lw;
        #pragma unroll
        for (int d = 1; d < 32; d <<= 1) m2 = fmaxf(m2, __shfl_xor(m2, d));
        float e2 = expf(lw - m2), s2 = e2;
        #pragma unroll
        for (int d = 1; d < 32; d <<= 1) s2 += __shfl_xor(s2, d);
        float pn = lw - m2 - logf(s2);
        pnew[p2] = pn;
        p_buf[p2 * BB + b] = pn;
    }
    __syncthreads();

    // reduce 16 dpl partials at resampled rows
    {
        int src = idxs[p] * BB + b;
        float d = dpl[j * 2048 + src] + dpl[(j + 8) * 2048 + src];
        d += __shfl_xor(d, 1); d += __shfl_xor(d, 2); d += __shfl_xor(d, 4);
        if (j == 0) dpart[p] = d;
    }
    __syncthreads();

    if (tid < 32) {
        float dd = dpart[tid];
        float bl = b_lab[0];
        pf_out_t[tid * BB + b] = 1.0f / (1.0f + expf(-(dd + bl)));
        float contrib = expf(pnew[tid]) * dd;
        #pragma unroll
        for (int d = 1; d < 32; d <<= 1) contrib += __shfl_xor(contrib, d);
        if (tid == 0) y_out_t[b] = 1.0f / (1.0f + expf(-(contrib + bl)));
    }
}

// ---------------------------------------------------------------------------
extern "C" void kernel_launch(void* const* d_in, const int* in_sizes, int n_in,
                              void* d_out, int out_size, void* d_ws, size_t ws_size,
                              hipStream_t stream)
{
    const float* prev_window = (const float*)d_in[0];   // (B,T,W)
    const float* h0    = (const float*)d_in[1];         // (P*B,H)
    const float* c0    = (const float*)d_in[2];
    const float* eps   = (const float*)d_in[3];         // (T,P*B,H)
    const float* gum   = (const float*)d_in[4];         // (T,B,P,P)
    const float* W_act = (const float*)d_in[5];
    const float* b_act = (const float*)d_in[6];
    const float* W_ih  = (const float*)d_in[7];
    const float* b_ih  = (const float*)d_in[8];
    const float* W_hh  = (const float*)d_in[9];
    const float* b_hh  = (const float*)d_in[10];
    const float* W_obs = (const float*)d_in[11];        // (320,1)
    const float* b_obs = (const float*)d_in[12];
    const float* W_lab = (const float*)d_in[13];        // (256,1)
    const float* b_lab = (const float*)d_in[14];

    float* out = (float*)d_out;       // [T*B] y_out then [T*P*B] pf_out
    float* ws  = (float*)d_ws;

    float* embT = ws;                         // 409600
    float* xobs = embT + 409600;              // 6400
    float* Wp2  = xobs + 6400;                // 460800
    float* h1a  = Wp2 + 460800;               // 524288
    float* c1a  = h1a + 524288;
    float* h1b  = c1a + 524288;
    float* c1b  = h1b + 524288;
    float* pb   = c1b + 524288;               // 2048
    int*   gidx = (int*)(pb + 2048);          // 2048
    float* dpo  = (float*)(gidx + 2048);      // 32768
    float* dpl  = dpo + 32768;                // 32768

    k_emb<<<1600, 256, 0, stream>>>(prev_window, W_act, b_act, W_obs, b_obs, embT, xobs);
    k_pack<<<1800, 256, 0, stream>>>(W_ih, W_hh, Wp2);

    for (int t = 0; t < TT; ++t) {
        const float* hi = (t == 0) ? h0 : ((t & 1) ? h1a : h1b);
        const float* ci = (t == 0) ? c0 : ((t & 1) ? c1a : c1b);
        float* ho = (t & 1) ? h1b : h1a;
        float* co = (t & 1) ? c1b : c1a;
        const int* gi = (t == 0) ? nullptr : gidx;

        s1_kernel<<<dim3(32, 16), 256, 0, stream>>>(
            hi, ci, gi, embT + (size_t)t * BB * EE,
            Wp2, b_ih, b_hh, W_obs, W_lab,
            eps + (size_t)t * PP * BB * HH,
            ho, co, dpo, dpl);

        s2_kernel<<<64, 256, 0, stream>>>(
            dpo, dpl, xobs + t * BB, gum + (size_t)t * BB * PP * PP,
            b_lab, pb, (t == 0) ? 1 : 0, gidx,
            out + (size_t)t * BB,
            out + (size_t)TT * BB + (size_t)t * PP * BB);
    }
}

// Round 5
// 7385.176 us; speedup vs baseline: 1.4190x; 1.4190x over previous
//
#include <hip/hip_runtime.h>
#include <hip/hip_bf16.h>
#include <cstddef>
#include <cstdint>

#define PP 32
#define BB 64
#define TT 100
#define WW 50
#define EE 64
#define HH 256
// ALPHA = 0.5, (1-ALPHA)/P = 0.015625

typedef float f4 __attribute__((ext_vector_type(4)));
typedef __attribute__((ext_vector_type(8))) short short8;   // 8 bf16 (4 VGPRs)
typedef __attribute__((ext_vector_type(4))) float f32x4;

__device__ __forceinline__ float sigm(float x) { return 1.0f / (1.0f + expf(-x)); }
__device__ __forceinline__ float splus(float x) {
    return fmaxf(x, 0.0f) + log1pf(expf(-fabsf(x)));
}
__device__ __forceinline__ unsigned short bfh(float x) {
    __hip_bfloat16 h = __float2bfloat16(x);           // RNE
    return *reinterpret_cast<unsigned short*>(&h);
}
__device__ __forceinline__ float bff(unsigned short u) {
    __hip_bfloat16 h; *reinterpret_cast<unsigned short*>(&h) = u;
    return __bfloat162float(h);
}

// ---------------------------------------------------------------------------
// Prologue A: emb = relu(prev_window @ W_act + b_act) -> bf16 hi/lo split
// [t][b][e]; xobs[t*64+b] = emb . W_obs[256:320] + b_obs (fp32 exact path)
// ---------------------------------------------------------------------------
__global__ __launch_bounds__(256) void k_emb(
    const float* __restrict__ pw, const float* __restrict__ w_act,
    const float* __restrict__ b_act, const float* __restrict__ w_obs,
    const float* __restrict__ b_obs,
    unsigned short* __restrict__ embh, unsigned short* __restrict__ embl,
    float* __restrict__ xobs)
{
    int tid = threadIdx.x;
    int sub = tid >> 6;
    int e   = tid & 63;
    int bt  = blockIdx.x * 4 + sub;   // = b*100 + t
    int b = bt / TT, t = bt % TT;

    __shared__ float pws[4][WW + 2];
    if (e < WW) pws[sub][e] = pw[(size_t)bt * WW + e];
    __syncthreads();

    float acc = b_act[e];
    #pragma unroll 5
    for (int w = 0; w < WW; ++w) acc += pws[sub][w] * w_act[w * EE + e];
    float r = fmaxf(acc, 0.0f);

    unsigned short uh = bfh(r);
    embh[((size_t)t * BB + b) * EE + e] = uh;
    embl[((size_t)t * BB + b) * EE + e] = bfh(r - bff(uh));

    float xv = r * w_obs[HH + e];
    #pragma unroll
    for (int d = 1; d < 64; d <<= 1) xv += __shfl_xor(xv, d);
    if (e == 0) xobs[t * BB + b] = xv + b_obs[0];
}

// ---------------------------------------------------------------------------
// Prologue B: pack weights into MFMA-fragment order, bf16 hi/lo.
// Layout: [colp 16][bidx 20][g 5][lane 64][e 8] (ushort).
//   bidx 0..9  = hi chunks (k = bidx*32 + (lane>>4)*8 + e)
//   bidx 10..19 = lo chunks (k = (bidx-10)*32 + ...)
//   col = g*256 + colp*16 + (lane&15); k<256 from W_hh, else W_ih.
// ---------------------------------------------------------------------------
__global__ __launch_bounds__(256) void k_packB(
    const float* __restrict__ W_ih, const float* __restrict__ W_hh,
    unsigned short* __restrict__ Bp)
{
    int i = blockIdx.x * 256 + threadIdx.x;    // 819200 total
    int colp = i / 51200;  int r = i - colp * 51200;
    int bidx = r / 2560;   r -= bidx * 2560;
    int g    = r / 512;    r -= g * 512;
    int lane = r >> 3;     int e = r & 7;

    int c = (bidx < 10) ? bidx : (bidx - 10);
    int k = c * 32 + (lane >> 4) * 8 + e;
    int col = g * HH + colp * 16 + (lane & 15);
    float w = (k < HH) ? W_hh[(size_t)k * 1280 + col]
                       : W_ih[(size_t)(k - HH) * 1280 + col];
    unsigned short uh = bfh(w);
    Bp[i] = (bidx < 10) ? uh : bfh(w - bff(uh));
}

// ---------------------------------------------------------------------------
// Prologue C: split h0 into bf16 hi/lo (into parity-A h buffers); copy c0.
// ---------------------------------------------------------------------------
__global__ __launch_bounds__(256) void k_split0(
    const float* __restrict__ h0, const float* __restrict__ c0,
    unsigned short* __restrict__ hh, unsigned short* __restrict__ hl,
    float* __restrict__ cc)
{
    int i = blockIdx.x * 256 + threadIdx.x;    // 524288
    float v = h0[i];
    unsigned short uh = bfh(v);
    hh[i] = uh;
    hl[i] = bfh(v - bff(uh));
    cc[i] = c0[i];
}

// ---------------------------------------------------------------------------
// Grid-wide barrier: monotone counter (memset to 0 each launch).
// ---------------------------------------------------------------------------
__device__ __forceinline__ void gsync(unsigned* bar, unsigned phase) {
    __syncthreads();
    if (threadIdx.x == 0) {
        __threadfence();
        __hip_atomic_fetch_add(bar, 1u, __ATOMIC_ACQ_REL, __HIP_MEMORY_SCOPE_AGENT);
        unsigned tgt = phase * 256u;
        while (__hip_atomic_load(bar, __ATOMIC_ACQUIRE, __HIP_MEMORY_SCOPE_AGENT) < tgt) {
            __builtin_amdgcn_s_sleep(8);
        }
        __threadfence();
    }
    __syncthreads();
}

// ---------------------------------------------------------------------------
// Main persistent kernel: 256 blocks x 256 threads, 1 block/CU.
// Block (rp, cp): rows rp*128..+128 (of P*B=2048), h-cols cp*16..+16
//   (gate-cols g*256 + hcol for g=0..4).
// B panel (20 chunks x 5 gates x 64 lanes x 16B = 100KB) persistent in LDS.
// GEMM: K_eff = 960 = [Ah|Ah|Al] x [Bh;Bl;Bh], 30 chunks of K=32,
//   mfma_f32_16x16x32_bf16, A-frags direct from global (coalesced,
//   gather-on-read via gidx), zero intra-step barriers.
// ---------------------------------------------------------------------------
__global__ __launch_bounds__(256, 1) void pf_main(
    const unsigned short* __restrict__ Bp,
    const unsigned short* __restrict__ embh, const unsigned short* __restrict__ embl,
    unsigned short* __restrict__ hhA, unsigned short* __restrict__ hlA,
    unsigned short* __restrict__ hhB, unsigned short* __restrict__ hlB,
    float* __restrict__ cA, float* __restrict__ cB,
    const float* __restrict__ b_ih, const float* __restrict__ b_hh,
    const float* __restrict__ w_obs, const float* __restrict__ w_lab,
    const float* __restrict__ eps, const float* __restrict__ gum,
    const float* __restrict__ xobs, const float* __restrict__ b_lab,
    float* __restrict__ pbuf, int* __restrict__ gidx,
    float* __restrict__ dpo, float* __restrict__ dpl,
    float* __restrict__ y_out, float* __restrict__ pf_out,
    unsigned* __restrict__ bar)
{
    __shared__ unsigned short Blds[51200];    // 100KB persistent B panel
    __shared__ float s2gt[PP][PP + 1];
    __shared__ float s2lg[PP], s2w1[PP], s2lgt[PP], s2pn[PP], s2dp[PP];
    __shared__ int   s2idx[PP];

    const int tid  = threadIdx.x;
    const int bid  = blockIdx.x;
    const int rp   = bid >> 4;      // 0..15
    const int cp   = bid & 15;      // 0..15
    const int lane = tid & 63;
    const int wu   = tid >> 6;      // 0..3
    const int lh   = lane & 15;
    const int kq   = lane >> 4;     // 0..3
    const int R0w  = rp * 128 + wu * 32;

    // ---- load persistent B slab (linear copy)
    {
        const short8* src = (const short8*)(Bp + (size_t)cp * 51200);
        short8* dst = (short8*)Blds;
        #pragma unroll 5
        for (int s = tid; s < 6400; s += 256) dst[s] = src[s];
    }

    // per-lane invariants
    const int hcol = cp * 16 + lh;
    float bsum[5];
    #pragma unroll
    for (int g = 0; g < 5; ++g) bsum[g] = b_ih[g * HH + hcol] + b_hh[g * HH + hcol];
    const float wobs_l = w_obs[hcol];
    const float wlab_l = w_lab[hcol];
    const float blab   = b_lab[0];

    __syncthreads();
    unsigned ph = 0;

    for (int t = 0; t < TT; ++t) {
        const unsigned short* hh_in = (t & 1) ? hhB : hhA;
        const unsigned short* hl_in = (t & 1) ? hlB : hlA;
        const float*          c_in  = (t & 1) ? cB  : cA;
        unsigned short* hh_out = (t & 1) ? hhA : hhB;
        unsigned short* hl_out = (t & 1) ? hlA : hlB;
        float*          c_out  = (t & 1) ? cA  : cB;

        // ---------------- S1: GEMM (K_eff = 960) ----------------
        size_t hbase[2], ebase[2];
        #pragma unroll
        for (int fr = 0; fr < 2; ++fr) {
            int myrow = R0w + fr * 16 + lh;
            int sr = (t == 0) ? myrow : gidx[myrow];
            hbase[fr] = (size_t)sr * 512 + (size_t)kq * 16;            // bytes
            ebase[fr] = (size_t)t * 8192 + (size_t)(myrow & 63) * 128 + (size_t)kq * 16;
        }

        f32x4 acc[2][5];
        #pragma unroll
        for (int fr = 0; fr < 2; ++fr)
            #pragma unroll
            for (int g = 0; g < 5; ++g) acc[fr][g] = (f32x4)(0.0f);

        const char* hhp = (const char*)hh_in;
        const char* hlp = (const char*)hl_in;
        const char* ehp = (const char*)embh;
        const char* elp = (const char*)embl;

        #pragma unroll
        for (int c = 0; c < 30; ++c) {
            const int  csrc = (c < 10) ? c : ((c < 20) ? c - 10 : c - 20);
            const bool hi   = (c < 20);
            short8 afr[2];
            #pragma unroll
            for (int fr = 0; fr < 2; ++fr) {
                const char* p;
                if (csrc < 8) p = (hi ? hhp : hlp) + hbase[fr] + csrc * 64;
                else          p = (hi ? ehp : elp) + ebase[fr] + (csrc - 8) * 64;
                afr[fr] = *(const short8*)p;
            }
            const int bidx = (c < 20) ? c : (c - 20);
            const short8* bb = (const short8*)Blds + (size_t)(bidx * 5) * 64 + lane;
            short8 bfr[5];
            #pragma unroll
            for (int g = 0; g < 5; ++g) bfr[g] = bb[g * 64];
            #pragma unroll
            for (int fr = 0; fr < 2; ++fr)
                #pragma unroll
                for (int g = 0; g < 5; ++g)
                    acc[fr][g] = __builtin_amdgcn_mfma_f32_16x16x32_bf16(
                        afr[fr], bfr[g], acc[fr][g], 0, 0, 0);
        }

        // ---------------- epilogue (C-layout: col=lane&15, row=(lane>>4)*4+reg)
        #pragma unroll
        for (int fr = 0; fr < 2; ++fr) {
            #pragma unroll
            for (int reg = 0; reg < 4; ++reg) {
                int row = R0w + fr * 16 + kq * 4 + reg;
                int sr  = (t == 0) ? row : gidx[row];
                float cpv = c_in[(size_t)sr * HH + hcol];
                float ep  = eps[(size_t)t * 524288 + (size_t)row * HH + hcol];

                float gi = acc[fr][0][reg] + bsum[0];
                float gf = acc[fr][1][reg] + bsum[1];
                float gg = acc[fr][2][reg] + bsum[2];
                float go = acc[fr][3][reg] + bsum[3];
                float gv = acc[fr][4][reg] + bsum[4];

                float mu  = sigm(gf) * cpv + sigm(gi) * tanhf(gg);
                float c1v = mu + splus(gv) * ep;
                float h1v = sigm(go) * tanhf(c1v);

                c_out[(size_t)row * HH + hcol] = c1v;
                unsigned short uh = bfh(h1v);
                hh_out[(size_t)row * HH + hcol] = uh;
                hl_out[(size_t)row * HH + hcol] = bfh(h1v - bff(uh));

                float po = h1v * wobs_l, pl = h1v * wlab_l;
                po += __shfl_xor(po, 1); po += __shfl_xor(po, 2);
                po += __shfl_xor(po, 4); po += __shfl_xor(po, 8);
                pl += __shfl_xor(pl, 1); pl += __shfl_xor(pl, 2);
                pl += __shfl_xor(pl, 4); pl += __shfl_xor(pl, 8);
                if (lh == 0) {
                    dpo[cp * 2048 + row] = po;
                    dpl[cp * 2048 + row] = pl;
                }
            }
        }

        gsync(bar, ++ph);   // dpo/dpl, h/c outputs visible device-wide

        // ---------------- S2: resample (blocks 0..63, one per batch col)
        if (bid < BB) {
            int b = bid;
            {
                f4 v = ((const f4*)(gum + (size_t)t * 65536 + (size_t)b * 1024))[tid];
                int p = tid >> 3, j0 = (tid & 7) * 4;
                s2gt[p][j0 + 0] = v.x; s2gt[p][j0 + 1] = v.y;
                s2gt[p][j0 + 2] = v.z; s2gt[p][j0 + 3] = v.w;
            }
            int p = tid >> 3, j = tid & 7;
            {
                int o = p * BB + b;
                float s = dpo[j * 2048 + o] + dpo[(j + 8) * 2048 + o];
                s += __shfl_xor(s, 1); s += __shfl_xor(s, 2); s += __shfl_xor(s, 4);
                if (j == 0) {
                    float pprev = (t == 0) ? -3.4657359027997265f : pbuf[o];
                    s2lg[p] = pprev + s + xobs[t * BB + b];
                }
            }
            __syncthreads();

            if (tid < 32) {
                float v = s2lg[tid];
                float m = v;
                #pragma unroll
                for (int d = 1; d < 32; d <<= 1) m = fmaxf(m, __shfl_xor(m, d));
                float e = expf(v - m), se = e;
                #pragma unroll
                for (int d = 1; d < 32; d <<= 1) se += __shfl_xor(se, d);
                float w1 = expf(v - m - logf(se));
                s2w1[tid]  = w1;
                s2lgt[tid] = logf(0.5f * w1 + 0.015625f);
            }
            __syncthreads();

            if (tid < 32) {
                int p2 = tid;
                float best = -INFINITY; int bi = 0;
                #pragma unroll 8
                for (int jj = 0; jj < 32; ++jj) {
                    float val = s2lgt[jj] + s2gt[p2][jj];
                    if (val > best) { best = val; bi = jj; }   // first max
                }
                s2idx[p2] = bi;
                gidx[p2 * BB + b] = bi * BB + b;

                float wv = s2w1[bi];
                wv = wv / (0.5f * wv + 0.015625f);
                float lw = logf(wv);
                float m2 = lw;
                #pragma unroll
                for (int d = 1; d < 32; d <<= 1) m2 = fmaxf(m2, __shfl_xor(m2, d));
                float e2 = expf(lw - m2), s2s = e2;
                #pragma unroll
                for (int d = 1; d < 32; d <<= 1) s2s += __shfl_xor(s2s, d);
                float pn = lw - m2 - logf(s2s);
                s2pn[p2] = pn;
                pbuf[p2 * BB + b] = pn;
            }
            __syncthreads();

            {
                int src = s2idx[p] * BB + b;
                float d2 = dpl[j * 2048 + src] + dpl[(j + 8) * 2048 + src];
                d2 += __shfl_xor(d2, 1); d2 += __shfl_xor(d2, 2); d2 += __shfl_xor(d2, 4);
                if (j == 0) s2dp[p] = d2;
            }
            __syncthreads();

            if (tid < 32) {
                float dd = s2dp[tid];
                pf_out[(size_t)t * 2048 + tid * BB + b] =
                    1.0f / (1.0f + expf(-(dd + blab)));
                float contrib = expf(s2pn[tid]) * dd;
                #pragma unroll
                for (int d = 1; d < 32; d <<= 1) contrib += __shfl_xor(contrib, d);
                if (tid == 0)
                    y_out[t * BB + b] = 1.0f / (1.0f + expf(-(contrib + blab)));
            }
        }

        gsync(bar, ++ph);   // gidx/pbuf visible for next step
    }
}

// ---------------------------------------------------------------------------
extern "C" void kernel_launch(void* const* d_in, const int* in_sizes, int n_in,
                              void* d_out, int out_size, void* d_ws, size_t ws_size,
                              hipStream_t stream)
{
    const float* prev_window = (const float*)d_in[0];
    const float* h0    = (const float*)d_in[1];
    const float* c0    = (const float*)d_in[2];
    const float* eps   = (const float*)d_in[3];
    const float* gum   = (const float*)d_in[4];
    const float* W_act = (const float*)d_in[5];
    const float* b_act = (const float*)d_in[6];
    const float* W_ih  = (const float*)d_in[7];
    const float* b_ih  = (const float*)d_in[8];
    const float* W_hh  = (const float*)d_in[9];
    const float* b_hh  = (const float*)d_in[10];
    const float* W_obs = (const float*)d_in[11];
    const float* b_obs = (const float*)d_in[12];
    const float* W_lab = (const float*)d_in[13];
    const float* b_lab = (const float*)d_in[14];

    float* out = (float*)d_out;           // [T*B] y_out, then [T*P*B] pf_out
    char* w = (char*)d_ws;

    unsigned short* Bp   = (unsigned short*)(w);               // 1,638,400 B
    unsigned short* embh = (unsigned short*)(w + 1638400);     //   819,200
    unsigned short* embl = (unsigned short*)(w + 2457600);     //   819,200
    unsigned short* hhA  = (unsigned short*)(w + 3276800);     // 1,048,576
    unsigned short* hlA  = (unsigned short*)(w + 4325376);
    unsigned short* hhB  = (unsigned short*)(w + 5373952);
    unsigned short* hlB  = (unsigned short*)(w + 6422528);
    float*  cA   = (float*)(w + 7471104);                      // 2,097,152
    float*  cB   = (float*)(w + 9568256);
    float*  xobs = (float*)(w + 11665408);                     //    25,600
    float*  pbuf = (float*)(w + 11691008);
    int*    gidx = (int*)(w + 11699200);
    float*  dpo  = (float*)(w + 11707392);                     //   131,072
    float*  dpl  = (float*)(w + 11838464);
    unsigned* bar = (unsigned*)(w + 11969536);

    k_emb<<<1600, 256, 0, stream>>>(prev_window, W_act, b_act, W_obs, b_obs,
                                    embh, embl, xobs);
    k_packB<<<3200, 256, 0, stream>>>(W_ih, W_hh, Bp);
    k_split0<<<2048, 256, 0, stream>>>(h0, c0, hhA, hlA, cA);
    hipMemsetAsync(bar, 0, 64, stream);

    pf_main<<<256, 256, 0, stream>>>(
        Bp, embh, embl, hhA, hlA, hhB, hlB, cA, cB,
        b_ih, b_hh, W_obs, W_lab, eps, gum, xobs, b_lab,
        pbuf, gidx, dpo, dpl, out, out + TT * BB, bar);
}

// Round 6
// 3636.632 us; speedup vs baseline: 2.8816x; 2.0308x over previous
//
#include <hip/hip_runtime.h>
#include <hip/hip_bf16.h>
#include <cstddef>
#include <cstdint>

#define PP 32
#define BB 64
#define TT 100
#define WW 50
#define EE 64
#define HH 256
// ALPHA = 0.5, (1-ALPHA)/P = 0.015625

typedef float f4 __attribute__((ext_vector_type(4)));
typedef __attribute__((ext_vector_type(8))) short short8;   // 8 bf16 (4 VGPRs)
typedef __attribute__((ext_vector_type(4))) float f32x4;

__device__ __forceinline__ float sigm(float x) { return 1.0f / (1.0f + expf(-x)); }
__device__ __forceinline__ float splus(float x) {
    return fmaxf(x, 0.0f) + log1pf(expf(-fabsf(x)));
}
__device__ __forceinline__ unsigned short bfh(float x) {
    __hip_bfloat16 h = __float2bfloat16(x);           // RNE
    return *reinterpret_cast<unsigned short*>(&h);
}
__device__ __forceinline__ float bff(unsigned short u) {
    __hip_bfloat16 h; *reinterpret_cast<unsigned short*>(&h) = u;
    return __bfloat162float(h);
}

// ---------------------------------------------------------------------------
// Prologue A: emb = relu(prev_window @ W_act + b_act) -> bf16 hi/lo split
// [t][b][e]; xobs[t*64+b] = emb . W_obs[256:320] + b_obs (fp32 exact path)
// ---------------------------------------------------------------------------
__global__ __launch_bounds__(256) void k_emb(
    const float* __restrict__ pw, const float* __restrict__ w_act,
    const float* __restrict__ b_act, const float* __restrict__ w_obs,
    const float* __restrict__ b_obs,
    unsigned short* __restrict__ embh, unsigned short* __restrict__ embl,
    float* __restrict__ xobs)
{
    int tid = threadIdx.x;
    int sub = tid >> 6;
    int e   = tid & 63;
    int bt  = blockIdx.x * 4 + sub;   // = b*100 + t
    int b = bt / TT, t = bt % TT;

    __shared__ float pws[4][WW + 2];
    if (e < WW) pws[sub][e] = pw[(size_t)bt * WW + e];
    __syncthreads();

    float acc = b_act[e];
    #pragma unroll 5
    for (int w = 0; w < WW; ++w) acc += pws[sub][w] * w_act[w * EE + e];
    float r = fmaxf(acc, 0.0f);

    unsigned short uh = bfh(r);
    embh[((size_t)t * BB + b) * EE + e] = uh;
    embl[((size_t)t * BB + b) * EE + e] = bfh(r - bff(uh));

    float xv = r * w_obs[HH + e];
    #pragma unroll
    for (int d = 1; d < 64; d <<= 1) xv += __shfl_xor(xv, d);
    if (e == 0) xobs[t * BB + b] = xv + b_obs[0];
}

// ---------------------------------------------------------------------------
// Prologue B: pack weights into MFMA-fragment order, bf16 hi/lo.
// Layout: [colp 16][bidx 20][g 5][lane 64][e 8] (ushort).
//   bidx 0..9  = hi chunks (k = bidx*32 + (lane>>4)*8 + e)
//   bidx 10..19 = lo chunks
//   col = g*256 + colp*16 + (lane&15); k<256 from W_hh, else W_ih.
// ---------------------------------------------------------------------------
__global__ __launch_bounds__(256) void k_packB(
    const float* __restrict__ W_ih, const float* __restrict__ W_hh,
    unsigned short* __restrict__ Bp)
{
    int i = blockIdx.x * 256 + threadIdx.x;    // 819200 total
    int colp = i / 51200;  int r = i - colp * 51200;
    int bidx = r / 2560;   r -= bidx * 2560;
    int g    = r / 512;    r -= g * 512;
    int lane = r >> 3;     int e = r & 7;

    int c = (bidx < 10) ? bidx : (bidx - 10);
    int k = c * 32 + (lane >> 4) * 8 + e;
    int col = g * HH + colp * 16 + (lane & 15);
    float w = (k < HH) ? W_hh[(size_t)k * 1280 + col]
                       : W_ih[(size_t)(k - HH) * 1280 + col];
    unsigned short uh = bfh(w);
    Bp[i] = (bidx < 10) ? uh : bfh(w - bff(uh));
}

// ---------------------------------------------------------------------------
// Prologue C: split h0 into bf16 hi/lo (into parity-A h buffers); copy c0.
// ---------------------------------------------------------------------------
__global__ __launch_bounds__(256) void k_split0(
    const float* __restrict__ h0, const float* __restrict__ c0,
    unsigned short* __restrict__ hh, unsigned short* __restrict__ hl,
    float* __restrict__ cc)
{
    int i = blockIdx.x * 256 + threadIdx.x;    // 524288
    float v = h0[i];
    unsigned short uh = bfh(v);
    hh[i] = uh;
    hl[i] = bfh(v - bff(uh));
    cc[i] = c0[i];
}

// ---------------------------------------------------------------------------
// S1: MFMA GEMM + LSTM elementwise + partial output dots.  Per step.
// grid 512 blocks = (rp 0..31 [64 rows], cp 0..15 [16 hcols]) x 256 thr.
// Wave w owns rows rp*64 + w*16 .. +16 (one 16-row A frag) x 5 gate-frags.
// K_eff = 960 = [Ah|Ah|Al] x [Bh;Bl;Bh], 30 chunks of K=32.
// A-frags and B-frags load directly from global (B is in frag order, L2-hot).
// No LDS, no __syncthreads in the GEMM.
// ---------------------------------------------------------------------------
__global__ __launch_bounds__(256, 2) void s1_mfma(
    const unsigned short* __restrict__ Bp,
    const unsigned short* __restrict__ embh_t, const unsigned short* __restrict__ embl_t,
    const unsigned short* __restrict__ hh_in, const unsigned short* __restrict__ hl_in,
    const float* __restrict__ c_in,
    unsigned short* __restrict__ hh_out, unsigned short* __restrict__ hl_out,
    float* __restrict__ c_out,
    const int* __restrict__ gidx,            // null at t=0 (identity)
    const float* __restrict__ b_ih, const float* __restrict__ b_hh,
    const float* __restrict__ w_obs, const float* __restrict__ w_lab,
    const float* __restrict__ eps_t,
    float* __restrict__ dpo, float* __restrict__ dpl)   // [16][2048] each
{
    const int tid  = threadIdx.x;
    const int rp   = blockIdx.x >> 4;   // 0..31
    const int cp   = blockIdx.x & 15;   // 0..15
    const int lane = tid & 63;
    const int w    = tid >> 6;          // wave 0..3
    const int lh   = lane & 15;
    const int kq   = lane >> 4;         // 0..3
    const int R0   = rp * 64 + w * 16;

    // ---- A-frag base addresses (gather-on-read via gidx)
    const int myrow = R0 + lh;
    const int sr    = gidx ? gidx[myrow] : myrow;
    const size_t hbase = (size_t)sr * 512 + (size_t)kq * 16;            // bytes
    const size_t ebase = (size_t)(myrow & 63) * 128 + (size_t)kq * 16;  // bytes

    f32x4 acc[5];
    #pragma unroll
    for (int g = 0; g < 5; ++g) acc[g] = (f32x4)(0.0f);

    const char* hhp = (const char*)hh_in;
    const char* hlp = (const char*)hl_in;
    const char* ehp = (const char*)embh_t;
    const char* elp = (const char*)embl_t;
    const short8* bb_base = (const short8*)Bp + (size_t)cp * 6400;  // cp slab

    #pragma unroll
    for (int c = 0; c < 30; ++c) {
        const int  csrc = (c < 10) ? c : ((c < 20) ? c - 10 : c - 20);
        const bool hi   = (c < 20);
        const char* p;
        if (csrc < 8) p = (hi ? hhp : hlp) + hbase + csrc * 64;
        else          p = (hi ? ehp : elp) + ebase + (csrc - 8) * 64;
        short8 afr = *(const short8*)p;

        const int bidx = (c < 20) ? c : (c - 20);
        const short8* bb = bb_base + (size_t)(bidx * 5) * 64 + lane;
        #pragma unroll
        for (int g = 0; g < 5; ++g)
            acc[g] = __builtin_amdgcn_mfma_f32_16x16x32_bf16(
                afr, bb[g * 64], acc[g], 0, 0, 0);
    }

    // ---- epilogue (C-layout: col = lane&15, row = (lane>>4)*4 + reg)
    const int hcol = cp * 16 + lh;
    float bsum[5];
    #pragma unroll
    for (int g = 0; g < 5; ++g) bsum[g] = b_ih[g * HH + hcol] + b_hh[g * HH + hcol];
    const float wobs_l = w_obs[hcol];
    const float wlab_l = w_lab[hcol];

    #pragma unroll
    for (int reg = 0; reg < 4; ++reg) {
        int row = R0 + kq * 4 + reg;
        int sr2 = gidx ? gidx[row] : row;
        float cpv = c_in[(size_t)sr2 * HH + hcol];
        float ep  = eps_t[(size_t)row * HH + hcol];

        float gi = acc[0][reg] + bsum[0];
        float gf = acc[1][reg] + bsum[1];
        float gg = acc[2][reg] + bsum[2];
        float go = acc[3][reg] + bsum[3];
        float gv = acc[4][reg] + bsum[4];

        float mu  = sigm(gf) * cpv + sigm(gi) * tanhf(gg);
        float c1v = mu + splus(gv) * ep;
        float h1v = sigm(go) * tanhf(c1v);

        c_out[(size_t)row * HH + hcol] = c1v;
        unsigned short uh = bfh(h1v);
        hh_out[(size_t)row * HH + hcol] = uh;
        hl_out[(size_t)row * HH + hcol] = bfh(h1v - bff(uh));

        float po = h1v * wobs_l, pl = h1v * wlab_l;
        po += __shfl_xor(po, 1); po += __shfl_xor(po, 2);
        po += __shfl_xor(po, 4); po += __shfl_xor(po, 8);
        pl += __shfl_xor(pl, 1); pl += __shfl_xor(pl, 2);
        pl += __shfl_xor(pl, 4); pl += __shfl_xor(pl, 8);
        if (lh == 0) {
            dpo[cp * 2048 + row] = po;
            dpl[cp * 2048 + row] = pl;
        }
    }
}

// ---------------------------------------------------------------------------
// S2: per batch-column b (64 blocks x 256 thr): reduce 16 partial dots,
// log-softmax over P, gumbel-argmax, write gidx, emit pf_out and y_out.
// ---------------------------------------------------------------------------
__global__ __launch_bounds__(256) void s2_kernel(
    const float* __restrict__ dpo, const float* __restrict__ dpl,
    const float* __restrict__ xobs_t, const float* __restrict__ g_t,
    const float* __restrict__ b_lab,
    float* __restrict__ p_buf, int first,
    int* __restrict__ gidx_next,
    float* __restrict__ y_out_t, float* __restrict__ pf_out_t)
{
    int b   = blockIdx.x;
    int tid = threadIdx.x;

    __shared__ float gt[PP][PP + 1];
    __shared__ float lg[PP];
    __shared__ float w1s[PP];
    __shared__ float lgt[PP];
    __shared__ float pnew[PP];
    __shared__ float dpart[PP];
    __shared__ int   idxs[PP];

    // stage gumbel tile (32x32), 256 threads x 1 float4
    {
        f4 v = ((const f4*)(g_t + (size_t)b * 1024))[tid];
        int p = tid >> 3, j0 = (tid & 7) * 4;
        gt[p][j0 + 0] = v.x; gt[p][j0 + 1] = v.y;
        gt[p][j0 + 2] = v.z; gt[p][j0 + 3] = v.w;
    }

    int p = tid >> 3, j = tid & 7;
    // reduce 16 dpo partials: thread (p, j) takes ct = j and j+8
    {
        int o = p * BB + b;
        float s = dpo[j * 2048 + o] + dpo[(j + 8) * 2048 + o];
        s += __shfl_xor(s, 1); s += __shfl_xor(s, 2); s += __shfl_xor(s, 4);
        if (j == 0) {
            float pprev = first ? -3.4657359027997265f : p_buf[o];
            lg[p] = pprev + s + xobs_t[b];
        }
    }
    __syncthreads();

    // log-softmax over P; w1; logits
    if (tid < 32) {
        float v = lg[tid];
        float m = v;
        #pragma unroll
        for (int d = 1; d < 32; d <<= 1) m = fmaxf(m, __shfl_xor(m, d));
        float e = expf(v - m), se = e;
        #pragma unroll
        for (int d = 1; d < 32; d <<= 1) se += __shfl_xor(se, d);
        float l1 = v - m - logf(se);
        float w1 = expf(l1);
        w1s[tid] = w1;
        lgt[tid] = logf(0.5f * w1 + 0.015625f);
    }
    __syncthreads();

    // gumbel-argmax resample; new weights; p_new
    if (tid < 32) {
        int p2 = tid;
        float best = -INFINITY; int bi = 0;
        #pragma unroll 8
        for (int jj = 0; jj < 32; ++jj) {
            float val = lgt[jj] + gt[p2][jj];
            if (val > best) { best = val; bi = jj; }   // first max, like jnp.argmax
        }
        idxs[p2] = bi;
        gidx_next[p2 * BB + b] = bi * BB + b;

        float wv = w1s[bi];
        wv = wv / (0.5f * wv + 0.015625f);
        float lw = logf(wv);
        float m2 = lw;
        #pragma unroll
        for (int d = 1; d < 32; d <<= 1) m2 = fmaxf(m2, __shfl_xor(m2, d));
        float e2 = expf(lw - m2), s2 = e2;
        #pragma unroll
        for (int d = 1; d < 32; d <<= 1) s2 += __shfl_xor(s2, d);
        float pn = lw - m2 - logf(s2);
        pnew[p2] = pn;
        p_buf[p2 * BB + b] = pn;
    }
    __syncthreads();

    // reduce 16 dpl partials at resampled rows
    {
        int src = idxs[p] * BB + b;
        float d = dpl[j * 2048 + src] + dpl[(j + 8) * 2048 + src];
        d += __shfl_xor(d, 1); d += __shfl_xor(d, 2); d += __shfl_xor(d, 4);
        if (j == 0) dpart[p] = d;
    }
    __syncthreads();

    if (tid < 32) {
        float dd = dpart[tid];
        float bl = b_lab[0];
        pf_out_t[tid * BB + b] = 1.0f / (1.0f + expf(-(dd + bl)));
        float contrib = expf(pnew[tid]) * dd;
        #pragma unroll
        for (int d = 1; d < 32; d <<= 1) contrib += __shfl_xor(contrib, d);
        if (tid == 0) y_out_t[b] = 1.0f / (1.0f + expf(-(contrib + bl)));
    }
}

// ---------------------------------------------------------------------------
extern "C" void kernel_launch(void* const* d_in, const int* in_sizes, int n_in,
                              void* d_out, int out_size, void* d_ws, size_t ws_size,
                              hipStream_t stream)
{
    const float* prev_window = (const float*)d_in[0];
    const float* h0    = (const float*)d_in[1];
    const float* c0    = (const float*)d_in[2];
    const float* eps   = (const float*)d_in[3];
    const float* gum   = (const float*)d_in[4];
    const float* W_act = (const float*)d_in[5];
    const float* b_act = (const float*)d_in[6];
    const float* W_ih  = (const float*)d_in[7];
    const float* b_ih  = (const float*)d_in[8];
    const float* W_hh  = (const float*)d_in[9];
    const float* b_hh  = (const float*)d_in[10];
    const float* W_obs = (const float*)d_in[11];
    const float* b_obs = (const float*)d_in[12];
    const float* W_lab = (const float*)d_in[13];
    const float* b_lab = (const float*)d_in[14];

    float* out = (float*)d_out;           // [T*B] y_out, then [T*P*B] pf_out
    char* w = (char*)d_ws;

    unsigned short* Bp   = (unsigned short*)(w);               // 1,638,400 B
    unsigned short* embh = (unsigned short*)(w + 1638400);     //   819,200
    unsigned short* embl = (unsigned short*)(w + 2457600);     //   819,200
    unsigned short* hhA  = (unsigned short*)(w + 3276800);     // 1,048,576
    unsigned short* hlA  = (unsigned short*)(w + 4325376);
    unsigned short* hhB  = (unsigned short*)(w + 5373952);
    unsigned short* hlB  = (unsigned short*)(w + 6422528);
    float*  cA   = (float*)(w + 7471104);                      // 2,097,152
    float*  cB   = (float*)(w + 9568256);
    float*  xobs = (float*)(w + 11665408);                     //    25,600
    float*  pbuf = (float*)(w + 11691008);
    int*    gidx = (int*)(w + 11699200);
    float*  dpo  = (float*)(w + 11707392);                     //   131,072
    float*  dpl  = (float*)(w + 11838464);

    k_emb<<<1600, 256, 0, stream>>>(prev_window, W_act, b_act, W_obs, b_obs,
                                    embh, embl, xobs);
    k_packB<<<3200, 256, 0, stream>>>(W_ih, W_hh, Bp);
    k_split0<<<2048, 256, 0, stream>>>(h0, c0, hhA, hlA, cA);

    for (int t = 0; t < TT; ++t) {
        const unsigned short* hh_in = (t & 1) ? hhB : hhA;
        const unsigned short* hl_in = (t & 1) ? hlB : hlA;
        const float*          c_in  = (t & 1) ? cB  : cA;
        unsigned short* hh_out = (t & 1) ? hhA : hhB;
        unsigned short* hl_out = (t & 1) ? hlA : hlB;
        float*          c_out  = (t & 1) ? cA  : cB;

        s1_mfma<<<512, 256, 0, stream>>>(
            Bp, embh + (size_t)t * 4096, embl + (size_t)t * 4096,
            hh_in, hl_in, c_in, hh_out, hl_out, c_out,
            (t == 0) ? nullptr : gidx,
            b_ih, b_hh, W_obs, W_lab,
            eps + (size_t)t * 524288,
            dpo, dpl);

        s2_kernel<<<64, 256, 0, stream>>>(
            dpo, dpl, xobs + t * BB, gum + (size_t)t * 65536,
            b_lab, pbuf, (t == 0) ? 1 : 0, gidx,
            out + (size_t)t * BB,
            out + (size_t)TT * BB + (size_t)t * PP * BB);
    }
}